// Round 6
// baseline (567.272 us; speedup 1.0000x reference)
//
#include <hip/hip_runtime.h>

// numpy never contracts mul+add: products are rounded then added. File-wide.
// The sgemm dot uses __builtin_fmaf explicitly (OpenBLAS vfmadd231ps).
#pragma clang fp contract(off)

#define NN 512
#define DD 256

typedef int   int4v   __attribute__((ext_vector_type(4)));
typedef float float4v __attribute__((ext_vector_type(4)));

// ---------------------------------------------------------------------------
// Fused single-pass row kernel (arithmetic VERIFIED bit-exact R2/R3, absmax 0):
//   sq  = numpy f32 pairwise leaf128(x)+leaf128(x+128), AVX512 tree
//         ((q0+q1)+(q2+q3))+((q4+q5)+(q6+q7)) via staged A/B/P state machine
//   dot = OpenBLAS sgemm single-accumulator sequential-k FMA
// Codegen controls (R3, measured neutral but keeps VGPR bounded):
//   - anchor row via wave-uniform pointer -> s_load, SGPR feeds v_fma
//   - sched_barrier(0) per 16-elem stage caps load hoisting
// ---------------------------------------------------------------------------
__device__ __forceinline__ void row_pass(const float* __restrict__ x,
                                         const float* __restrict__ ar,  // uniform
                                         float& sq_out, float& dot_out)
{
    float dot = 0.0f;
    float leaf0 = 0.0f, leaf1 = 0.0f;
    #pragma unroll
    for (int l = 0; l < 2; ++l) {
        const float* __restrict__ xl = x + 128 * l;
        const float* __restrict__ al = ar + 128 * l;
        float A[16], B[16], P[16];
        #pragma unroll
        for (int q = 0; q < 8; ++q) {
            #pragma unroll
            for (int i0 = 0; i0 < 16; i0 += 4) {
                const int o = 16 * q + i0;
                const float4v v = *(const float4v*)(xl + o);
                dot = __builtin_fmaf(al[o + 0], v.x, dot);
                dot = __builtin_fmaf(al[o + 1], v.y, dot);
                dot = __builtin_fmaf(al[o + 2], v.z, dot);
                dot = __builtin_fmaf(al[o + 3], v.w, dot);
                #pragma unroll
                for (int j = 0; j < 4; ++j) {
                    const int i = i0 + j;
                    const float xx = (j == 0) ? v.x : (j == 1) ? v.y
                                   : (j == 2) ? v.z : v.w;
                    const float qq = xx * xx;
                    if      (q == 0) A[i] = qq;
                    else if (q == 1) A[i] = A[i] + qq;               // q0+q1
                    else if (q == 2) B[i] = qq;
                    else if (q == 3) { B[i] = B[i] + qq;             // q2+q3
                                       P[i] = A[i] + B[i]; }
                    else if (q == 4) A[i] = qq;
                    else if (q == 5) A[i] = A[i] + qq;               // q4+q5
                    else if (q == 6) B[i] = qq;
                    else             { B[i] = B[i] + qq;             // q6+q7
                                       P[i] = P[i] + (A[i] + B[i]); }
                }
            }
            __builtin_amdgcn_sched_barrier(0);
        }
        float qr[8];
        #pragma unroll
        for (int i = 0; i < 8; ++i) qr[i] = P[i] + P[i + 8];
        const float s0 = qr[0] + qr[4];
        const float s1 = qr[1] + qr[5];
        const float s2 = qr[2] + qr[6];
        const float s3 = qr[3] + qr[7];
        const float leaf = (s0 + s2) + (s1 + s3);
        if (l == 0) leaf0 = leaf; else leaf1 = leaf;
    }
    sq_out  = leaf0 + leaf1;
    dot_out = dot;
}

// ---------------------------------------------------------------------------
// Fused TripletMarginMiner. Store path = R0's NT/512-block structure (best
// measured; plain +35us, seg-split +35us, prologue opts neutral -> kernel is
// pure store-drain at ~4.0 TB/s vs fill's 6.2 TB/s). ONE change vs R3:
// PER-ANCHOR XOR-PERMUTED store order. All 512 blocks march their 1 MiB
// slabs in lockstep, so the instantaneous write-address set is a 1 MiB-
// periodic lattice {a MiB + delta} -> HBM channel hotspotting. XOR-ing each
// block's p-group index with phi(a)=(37*a)&127 (bijection on [0,128)) makes
// the concurrent write fronts uniformly spread over the whole 537 MB. Pure
// store-order permutation: same addresses, same values, same NT opcode ->
// absmax unaffected.
//
//   mat  : fl32(fl32(sq_a+sq_j) - fl32(2*dot)), relu.
//   mask : sames(a,p)&(p!=a)&diffs(a,n)&(fl32(mat_an-mat_ap) <= 0.2f)
//          validity folded: dn=+inf (diff fails), mp=NaN (same fails).
// Coalesced int4 NT stores, n fastest.
// ---------------------------------------------------------------------------
__global__ __launch_bounds__(512)
void triplet_kernel(const float* __restrict__ emb,
                    const int* __restrict__ lab,
                    int* __restrict__ out)
{
    __shared__ int   canon[NN];
    __shared__ float dn[NN];
    __shared__ float mp[NN];
    __shared__ float sq_a_sh;
    __shared__ int   det_lab64;

    const int a = blockIdx.x;
    const int t = threadIdx.x;   // 0..511

    // labels width canonicalization (values in [0,32): int64 staging has all
    // 256 odd int32 words zero; genuine int32 fails that w.p. 1-32^-256)
    if (t == 0) det_lab64 = 0;
    __syncthreads();
    if (t < 256 && lab[2 * t + 1] == 0) atomicAdd(&det_lab64, 1);
    __syncthreads();
    canon[t] = (det_lab64 == 256) ? lab[2 * t] : lab[t];

    // ---- sq_j + dot(a,j): single fused float4 pass, anchor row scalar ----
    const float* __restrict__ xr   = emb + (size_t)t * DD;
    const float* __restrict__ aptr = emb + (size_t)a * DD;   // wave-uniform
    float sqj, dot;
    row_pass(xr, aptr, sqj, dot);
    if (t == a) sq_a_sh = sqj;
    __syncthreads();   // sq_a_sh AND canon[] visible

    // ---- mat[a][t], f32, numpy op tree ----
    const float t1 = sq_a_sh + sqj;
    const float t2 = 2.0f * dot;       // exact scale
    float m = t1 - t2;
    m = m > 0.0f ? m : 0.0f;

    const int la = canon[a];
    dn[t] = (canon[t] != la) ? m : __builtin_inff();
    mp[t] = (canon[t] == la && t != a) ? m : __builtin_nanf("");
    __syncthreads();

    // ---- write the 512x512 int32 slab: NT int4, XOR-PERMUTED p order ----
    const int tx = t & 127;      // 4 consecutive n per thread
    const int ty = t >> 7;       // 0..3 strides p
    const float d0 = dn[4 * tx + 0];
    const float d1 = dn[4 * tx + 1];
    const float d2 = dn[4 * tx + 2];
    const float d3 = dn[4 * tx + 3];

    int4v* base = (int4v*)out + (size_t)a * NN * (NN / 4) + tx;
    const int phi = (a * 37) & 127;          // per-anchor permutation key
    for (int g = 0; g < 128; ++g) {
        const int p = ty + 4 * (g ^ phi);    // bijection on p-groups
        const float mpp = mp[p];             // LDS broadcast (p wave-uniform)
        int4v r;
        r.x = ((d0 - mpp) <= 0.2f) ? 1 : 0;  // inf/NaN fold validity to 0
        r.y = ((d1 - mpp) <= 0.2f) ? 1 : 0;
        r.z = ((d2 - mpp) <= 0.2f) ? 1 : 0;
        r.w = ((d3 - mpp) <= 0.2f) ? 1 : 0;
        __builtin_nontemporal_store(r, base + (size_t)p * (NN / 4));
    }
}

// ---------------------------------------------------------------------------
extern "C" void kernel_launch(void* const* d_in, const int* in_sizes, int n_in,
                              void* d_out, int out_size, void* d_ws, size_t ws_size,
                              hipStream_t stream)
{
    const float* emb    = (const float*)d_in[0];
    const int*   labels = (const int*)d_in[1];
    int*         out    = (int*)d_out;
    (void)d_ws; (void)ws_size;   // deliberately unused: ws use costs ~+30us

    triplet_kernel<<<NN, 512, 0, stream>>>(emb, labels, out);
}